// Round 1
// baseline (954.813 us; speedup 1.0000x reference)
//
#include <hip/hip_runtime.h>
#include <stdint.h>

// D = 4096, TOKENS = (4,2048) -> M = 8192. All dims compile-time except M.
#define DD 4096
#define NE_IDX 3277   // round(4096*0.8)

typedef __attribute__((ext_vector_type(8))) short short8;
typedef __attribute__((ext_vector_type(4))) float f32x4;
typedef __attribute__((ext_vector_type(4))) unsigned int u32x4;

__device__ __forceinline__ unsigned short f2bf(float f) {
    // round-to-nearest-even bf16 (finite inputs only)
    unsigned int u = __float_as_uint(f);
    u += 0x7fffu + ((u >> 16) & 1u);
    return (unsigned short)(u >> 16);
}

__device__ __forceinline__ void gload16(const void* g, void* l) {
    __builtin_amdgcn_global_load_lds(
        (const __attribute__((address_space(1))) unsigned int*)g,
        (__attribute__((address_space(3))) unsigned int*)l,
        16, 0, 0);
}

// ---------------------------------------------------------------------------
// Detect element width of the boolean kernel arrays.
// flag=1: 4-byte elements (int32 0/1 or fp32 0.0/1.0 -> nonzero test works for both)
// flag=0: 1-byte elements (raw numpy bool)
// Packed 0/1 bytes read as u32 are in {0,1,0x3f800000} for all 256 samples with
// probability ~8^-256 -> detection is reliable.
// ---------------------------------------------------------------------------
__global__ void detect_kernel(const unsigned int* __restrict__ k0, int* __restrict__ flag) {
    if (blockIdx.x == 0 && threadIdx.x == 0) {
        int ok4 = 1;
        for (int i = 0; i < 256; ++i) {
            unsigned int v = k0[i];
            if (!(v == 0u || v == 1u || v == 0x3f800000u)) { ok4 = 0; break; }
        }
        *flag = ok4;
    }
}

// ---------------------------------------------------------------------------
// x (fp32) -> bf16, vectorized 8/thread
// ---------------------------------------------------------------------------
__global__ void pack_x_kernel(const float* __restrict__ x, unsigned short* __restrict__ xb, int n8) {
    const int stride = gridDim.x * blockDim.x;
    for (int i = blockIdx.x * blockDim.x + threadIdx.x; i < n8; i += stride) {
        const float4* p = (const float4*)(x + (size_t)i * 8);
        float4 a = p[0], b = p[1];
        short8 r;
        r[0] = (short)f2bf(a.x); r[1] = (short)f2bf(a.y);
        r[2] = (short)f2bf(a.z); r[3] = (short)f2bf(a.w);
        r[4] = (short)f2bf(b.x); r[5] = (short)f2bf(b.y);
        r[6] = (short)f2bf(b.z); r[7] = (short)f2bf(b.w);
        *(short8*)(xb + (size_t)i * 8) = r;
    }
}

// ---------------------------------------------------------------------------
// Pack weights transposed with folded scale:
//   wt[j*DD + i] = s * (i < ne ? 1 : inh) * (k[i][j] ? 1 : -1)
// s = 1/64, inh = -4 -> magnitudes 2^-6 / 2^-4, exact in bf16.
// 64x64 tile transpose through LDS. grid = (DD/64, DD/64), 256 threads.
// ---------------------------------------------------------------------------
__global__ void pack_w_kernel(const void* __restrict__ kin, unsigned short* __restrict__ wt,
                              const float* __restrict__ sptr, float inh, int ne,
                              const int* __restrict__ flag) {
    __shared__ unsigned short tile[64][68];
    const int elem4 = *flag;
    const float s = *sptr;
    const int i0 = blockIdx.x * 64;
    const int j0 = blockIdx.y * 64;
    const int t = threadIdx.x;

    // phase 1: coalesced read of k[i][j], 16 j-values per thread, scale by row i
    {
        const int il = t >> 2;
        const int jc = (t & 3) * 16;
        const int gi = i0 + il;
        const float mag = s * ((gi < ne) ? 1.0f : inh);
        const unsigned short pos = f2bf(mag);
        const unsigned short neg = f2bf(-mag);
        if (elem4) {
            const unsigned int* k32 = (const unsigned int*)kin + (size_t)gi * DD + j0 + jc;
            #pragma unroll
            for (int q = 0; q < 4; ++q) {
                u32x4 v = *(const u32x4*)(k32 + q * 4);
                #pragma unroll
                for (int e = 0; e < 4; ++e)
                    tile[il][jc + q * 4 + e] = v[e] ? pos : neg;
            }
        } else {
            const unsigned char* k8 = (const unsigned char*)kin + (size_t)gi * DD + j0 + jc;
            u32x4 v = *(const u32x4*)k8;  // 16 bytes
            #pragma unroll
            for (int q = 0; q < 4; ++q) {
                unsigned int w = v[q];
                tile[il][jc + q * 4 + 0] = (w & 0xffu) ? pos : neg;
                tile[il][jc + q * 4 + 1] = ((w >> 8) & 0xffu) ? pos : neg;
                tile[il][jc + q * 4 + 2] = ((w >> 16) & 0xffu) ? pos : neg;
                tile[il][jc + q * 4 + 3] = ((w >> 24) & 0xffu) ? pos : neg;
            }
        }
    }
    __syncthreads();
    // phase 2: write wt[j][i], coalesced rows of 64 i-values
    {
        const int jl = t >> 2;
        const int ic = (t & 3) * 16;
        short8 o0, o1;
        #pragma unroll
        for (int e = 0; e < 8; ++e) o0[e] = (short)tile[ic + e][jl];
        #pragma unroll
        for (int e = 0; e < 8; ++e) o1[e] = (short)tile[ic + 8 + e][jl];
        unsigned short* dst = wt + (size_t)(j0 + jl) * DD + i0 + ic;
        *(short8*)(dst) = o0;
        *(short8*)(dst + 8) = o1;
    }
}

// ---------------------------------------------------------------------------
// bf16 GEMM, m97 structure: 128x128 tile, BK=64, 4 waves (2x2), 16x16x32 MFMA,
// global_load_lds width-16 staging, T2 XOR swizzle (pre-swizzled source chunk +
// swizzled ds_read), XCD-aware block swizzle. N=K=4096 fixed, M runtime.
// MODE 1: out = bf16(relu(acc)*2).  MODE 0: out = fp32 acc.
// ---------------------------------------------------------------------------
template <int MODE>
__global__ __launch_bounds__(256, 2)
void gemm_kernel(const unsigned short* __restrict__ A,   // M x 4096 bf16
                 const unsigned short* __restrict__ Bt,  // 4096 x 4096 bf16 (N x K)
                 void* __restrict__ Cout)
{
    __shared__ unsigned short As[128 * 64];
    __shared__ unsigned short Bs[128 * 64];

    const int tid  = threadIdx.x;
    const int lane = tid & 63;
    const int wave = tid >> 6;
    const int wr   = wave >> 1;      // 0..1 : wave row
    const int wc   = wave & 1;       // 0..1 : wave col

    // XCD swizzle: grid = (M/128)*32, divisible by 8
    int wg = blockIdx.x;
    const int per = gridDim.x >> 3;
    wg = (wg & 7) * per + (wg >> 3);
    const int tm = wg >> 5;          // M-tile
    const int tn = wg & 31;          // N-tile

    const int lr = lane >> 3;              // row within 8-row segment
    const int lc = (lane & 7) ^ lr;        // inverse-swizzled source chunk
    const int fr = lane & 15;              // fragment row/col
    const int fg = lane >> 4;              // k-group 0..3

    const size_t a_row0 = (size_t)(tm * 128);
    const size_t b_row0 = (size_t)(tn * 128);

    f32x4 acc[4][4];
    #pragma unroll
    for (int m = 0; m < 4; ++m)
        #pragma unroll
        for (int n = 0; n < 4; ++n)
            acc[m][n] = (f32x4){0.f, 0.f, 0.f, 0.f};

    for (int kt = 0; kt < DD; kt += 64) {
        // stage: each wave stages 4 segments (8 rows x 128B) of A and of B
        #pragma unroll
        for (int s = 0; s < 4; ++s) {
            const int seg = wave * 4 + s;
            const int row = seg * 8 + lr;
            const unsigned short* ga = A  + ((a_row0 + row) << 12) + kt + lc * 8;
            const unsigned short* gb = Bt + ((b_row0 + row) << 12) + kt + lc * 8;
            gload16(ga, &As[seg * 512]);
            gload16(gb, &Bs[seg * 512]);
        }
        __syncthreads();  // vmcnt(0) drain + barrier

        #pragma unroll
        for (int kk = 0; kk < 64; kk += 32) {
            const int chunk = (kk >> 3) + fg;
            short8 af[4], bfr[4];
            #pragma unroll
            for (int m = 0; m < 4; ++m) {
                const int r = wr * 64 + m * 16 + fr;
                const int off = r * 128 + ((chunk * 16) ^ ((r & 7) << 4));
                af[m] = *(const short8*)((const char*)As + off);
            }
            #pragma unroll
            for (int n = 0; n < 4; ++n) {
                const int r = wc * 64 + n * 16 + fr;
                const int off = r * 128 + ((chunk * 16) ^ ((r & 7) << 4));
                bfr[n] = *(const short8*)((const char*)Bs + off);
            }
            #pragma unroll
            for (int m = 0; m < 4; ++m)
                #pragma unroll
                for (int n = 0; n < 4; ++n)
                    acc[m][n] = __builtin_amdgcn_mfma_f32_16x16x32_bf16(
                        af[m], bfr[n], acc[m][n], 0, 0, 0);
        }
        __syncthreads();
    }

    // epilogue: C/D layout col = lane&15, row = (lane>>4)*4 + reg
    const int orow0 = tm * 128 + wr * 64;
    const int ocol0 = tn * 128 + wc * 64;
    #pragma unroll
    for (int m = 0; m < 4; ++m) {
        #pragma unroll
        for (int n = 0; n < 4; ++n) {
            #pragma unroll
            for (int j = 0; j < 4; ++j) {
                const int row = orow0 + m * 16 + fg * 4 + j;
                const int col = ocol0 + n * 16 + fr;
                float v = acc[m][n][j];
                if (MODE == 1) {
                    v = fmaxf(v, 0.0f) * 2.0f;
                    ((unsigned short*)Cout)[((size_t)row << 12) + col] = f2bf(v);
                } else {
                    ((float*)Cout)[((size_t)row << 12) + col] = v;
                }
            }
        }
    }
}

// ---------------------------------------------------------------------------
extern "C" void kernel_launch(void* const* d_in, const int* in_sizes, int n_in,
                              void* d_out, int out_size, void* d_ws, size_t ws_size,
                              hipStream_t stream) {
    const float* x  = (const float*)d_in[0];
    const void*  k0 = d_in[1];
    const float* s0 = (const float*)d_in[2];
    const void*  k1 = d_in[3];
    const float* s1 = (const float*)d_in[4];
    const void*  k2 = d_in[5];
    const float* s2 = (const float*)d_in[6];

    const int M = in_sizes[0] / DD;   // 8192

    // workspace layout: xb (M*DD bf16, reused as h2) | h1 (M*DD bf16) | wt (DD*DD bf16) | flag
    const size_t act_bytes = (size_t)M * DD * 2;
    const size_t w_bytes   = (size_t)DD * DD * 2;
    const size_t need      = act_bytes * 2 + w_bytes + 256;
    if (ws_size < need) return;  // insufficient workspace — cannot compute

    char* ws = (char*)d_ws;
    unsigned short* xb = (unsigned short*)ws;                        // M x DD bf16 (later h2)
    unsigned short* h1 = (unsigned short*)(ws + act_bytes);          // M x DD bf16
    unsigned short* wt = (unsigned short*)(ws + act_bytes * 2);      // DD x DD bf16 (N x K)
    int* flag          = (int*)(ws + act_bytes * 2 + w_bytes);

    detect_kernel<<<1, 64, 0, stream>>>((const unsigned int*)k0, flag);
    pack_x_kernel<<<2048, 256, 0, stream>>>(x, xb, M * DD / 8);

    dim3 pw_grid(DD / 64, DD / 64);
    const int gemm_grid = (M / 128) * (DD / 128);   // 2048

    // layer 0: h1 = relu(s0 * x @ W0) * 2
    pack_w_kernel<<<pw_grid, 256, 0, stream>>>(k0, wt, s0, 1.0f, DD, flag);
    gemm_kernel<1><<<gemm_grid, 256, 0, stream>>>(xb, wt, h1);

    // layer 1: h2 = relu(ei_dense(h1, k1, s1)) * 2   (EI scale folded into wt)
    pack_w_kernel<<<pw_grid, 256, 0, stream>>>(k1, wt, s1, -4.0f, NE_IDX, flag);
    gemm_kernel<1><<<gemm_grid, 256, 0, stream>>>(h1, wt, xb);       // h2 -> xb

    // layer 2: out = ei_dense(h2, k2, s2), fp32
    pack_w_kernel<<<pw_grid, 256, 0, stream>>>(k2, wt, s2, -4.0f, NE_IDX, flag);
    gemm_kernel<0><<<gemm_grid, 256, 0, stream>>>(xb, wt, (float*)d_out);
}

// Round 2
// 855.580 us; speedup vs baseline: 1.1160x; 1.1160x over previous
//
#include <hip/hip_runtime.h>
#include <stdint.h>

// D = 4096, TOKENS = (4,2048) -> M = 8192.
#define DD 4096
#define NE_IDX 3277   // round(4096*0.8)

typedef __attribute__((ext_vector_type(8))) short short8;
typedef __attribute__((ext_vector_type(4))) float f32x4;
typedef __attribute__((ext_vector_type(4))) unsigned int u32x4;

__device__ __forceinline__ unsigned short f2bf(float f) {
    unsigned int u = __float_as_uint(f);
    u += 0x7fffu + ((u >> 16) & 1u);
    return (unsigned short)(u >> 16);
}

__device__ __forceinline__ void gload16(const void* g, void* l) {
    __builtin_amdgcn_global_load_lds(
        (const __attribute__((address_space(1))) unsigned int*)g,
        (__attribute__((address_space(3))) unsigned int*)l,
        16, 0, 0);
}

// ---------------------------------------------------------------------------
__global__ void detect_kernel(const unsigned int* __restrict__ k0, int* __restrict__ flag) {
    if (blockIdx.x == 0 && threadIdx.x == 0) {
        int ok4 = 1;
        for (int i = 0; i < 256; ++i) {
            unsigned int v = k0[i];
            if (!(v == 0u || v == 1u || v == 0x3f800000u)) { ok4 = 0; break; }
        }
        *flag = ok4;
    }
}

// ---------------------------------------------------------------------------
__global__ void pack_x_kernel(const float* __restrict__ x, unsigned short* __restrict__ xb, int n8) {
    const int stride = gridDim.x * blockDim.x;
    for (int i = blockIdx.x * blockDim.x + threadIdx.x; i < n8; i += stride) {
        const float4* p = (const float4*)(x + (size_t)i * 8);
        float4 a = p[0], b = p[1];
        short8 r;
        r[0] = (short)f2bf(a.x); r[1] = (short)f2bf(a.y);
        r[2] = (short)f2bf(a.z); r[3] = (short)f2bf(a.w);
        r[4] = (short)f2bf(b.x); r[5] = (short)f2bf(b.y);
        r[6] = (short)f2bf(b.z); r[7] = (short)f2bf(b.w);
        *(short8*)(xb + (size_t)i * 8) = r;
    }
}

// ---------------------------------------------------------------------------
// wt[j*DD + i] = s * (i < ne ? 1 : inh) * (k[i][j] ? 1 : -1), 64x64 LDS transpose
// ---------------------------------------------------------------------------
__global__ void pack_w_kernel(const void* __restrict__ kin, unsigned short* __restrict__ wt,
                              const float* __restrict__ sptr, float inh, int ne,
                              const int* __restrict__ flag) {
    __shared__ unsigned short tile[64][68];
    const int elem4 = *flag;
    const float s = *sptr;
    const int i0 = blockIdx.x * 64;
    const int j0 = blockIdx.y * 64;
    const int t = threadIdx.x;
    {
        const int il = t >> 2;
        const int jc = (t & 3) * 16;
        const int gi = i0 + il;
        const float mag = s * ((gi < ne) ? 1.0f : inh);
        const unsigned short pos = f2bf(mag);
        const unsigned short neg = f2bf(-mag);
        if (elem4) {
            const unsigned int* k32 = (const unsigned int*)kin + (size_t)gi * DD + j0 + jc;
            #pragma unroll
            for (int q = 0; q < 4; ++q) {
                u32x4 v = *(const u32x4*)(k32 + q * 4);
                #pragma unroll
                for (int e = 0; e < 4; ++e)
                    tile[il][jc + q * 4 + e] = v[e] ? pos : neg;
            }
        } else {
            const unsigned char* k8 = (const unsigned char*)kin + (size_t)gi * DD + j0 + jc;
            u32x4 v = *(const u32x4*)k8;
            #pragma unroll
            for (int q = 0; q < 4; ++q) {
                unsigned int w = v[q];
                tile[il][jc + q * 4 + 0] = (w & 0xffu) ? pos : neg;
                tile[il][jc + q * 4 + 1] = ((w >> 8) & 0xffu) ? pos : neg;
                tile[il][jc + q * 4 + 2] = ((w >> 16) & 0xffu) ? pos : neg;
                tile[il][jc + q * 4 + 3] = ((w >> 24) & 0xffu) ? pos : neg;
            }
        }
    }
    __syncthreads();
    {
        const int jl = t >> 2;
        const int ic = (t & 3) * 16;
        short8 o0, o1;
        #pragma unroll
        for (int e = 0; e < 8; ++e) o0[e] = (short)tile[ic + e][jl];
        #pragma unroll
        for (int e = 0; e < 8; ++e) o1[e] = (short)tile[ic + 8 + e][jl];
        unsigned short* dst = wt + (size_t)(j0 + jl) * DD + i0 + ic;
        *(short8*)(dst) = o0;
        *(short8*)(dst + 8) = o1;
    }
}

// ---------------------------------------------------------------------------
// 256x256 tile, BK=64, 8 waves (2Mx4N), 4-phase/K-tile deep pipeline.
// Per phase: 12 ds_read_b128 + 1 half-tile stage -> barrier -> lgkmcnt(0) ->
// 16 MFMA (setprio) -> vmcnt(4) -> barrier.  Stages of tile t+1 issued during
// tile t (idle LDS buffer); counted vmcnt keeps 2-3 half-tiles in flight.
// Chunk defs: A-chunk c = rows [c*64,+64) u [c*64+128,+64)  (mh=c rows, both wr)
//             B-chunk c = rows c*32 + [0,32) + 64k, k=0..3  (nh=c rows, all wc)
// Issue order per tile: A0 @p0, B0 @p1, B1 @p2, A1 @p3.
// Deadlines met: A0,B0 by boundary (vmcnt(4) leaves newest 2 = B1,A1);
// B1 by end p0; A1 by end p1 -- each forced by the per-phase vmcnt(4).
// ---------------------------------------------------------------------------
#define PHASE(MH, NH, STAGE_STMT) do {                                          \
    short8 af[2][4], bf[2][2];                                                  \
    _Pragma("unroll")                                                           \
    for (int kk = 0; kk < 2; ++kk) {                                            \
        _Pragma("unroll")                                                       \
        for (int m = 0; m < 4; ++m)                                             \
            af[kk][m] = *(const short8*)(abuf + (abase[(MH)*4+m] ^ ((kk*4+fg)<<4))); \
        _Pragma("unroll")                                                       \
        for (int n = 0; n < 2; ++n)                                             \
            bf[kk][n] = *(const short8*)(bbuf + (bbase[(NH)*2+n] ^ ((kk*4+fg)<<4))); \
    }                                                                           \
    STAGE_STMT;                                                                 \
    __builtin_amdgcn_s_barrier();                                               \
    asm volatile("s_waitcnt lgkmcnt(0)" ::: "memory");                          \
    __builtin_amdgcn_sched_barrier(0);                                          \
    __builtin_amdgcn_s_setprio(1);                                              \
    _Pragma("unroll")                                                           \
    for (int kk = 0; kk < 2; ++kk)                                              \
        _Pragma("unroll")                                                       \
        for (int m = 0; m < 4; ++m)                                             \
            _Pragma("unroll")                                                   \
            for (int n = 0; n < 2; ++n)                                         \
                acc[(MH)*4+m][(NH)*2+n] = __builtin_amdgcn_mfma_f32_16x16x32_bf16( \
                    af[kk][m], bf[kk][n], acc[(MH)*4+m][(NH)*2+n], 0, 0, 0);    \
    __builtin_amdgcn_s_setprio(0);                                              \
    __builtin_amdgcn_sched_barrier(0);                                          \
    asm volatile("s_waitcnt vmcnt(4)" ::: "memory");                            \
    __builtin_amdgcn_s_barrier();                                               \
    __builtin_amdgcn_sched_barrier(0);                                          \
} while (0)

template <int MODE>
__global__ __launch_bounds__(512, 2)
void gemm256_kernel(const unsigned short* __restrict__ A,   // M x 4096 bf16
                    const unsigned short* __restrict__ Bt,  // 4096 x 4096 bf16 (N x K)
                    void* __restrict__ Cout)
{
    __shared__ unsigned short L[65536];  // 128 KiB: buf0{A,B} buf1{A,B}, 16384 u16 each

    const int tid  = threadIdx.x;
    const int lane = tid & 63;
    const int fr   = lane & 15;
    const int fg   = lane >> 4;
    const int wave = tid >> 6;
    const int wr   = wave >> 2;    // 0..1
    const int wc   = wave & 3;     // 0..3

    // XCD swizzle (grid = 512, divisible by 8)
    int wg = blockIdx.x;
    const int per = gridDim.x >> 3;
    wg = (wg & 7) * per + (wg >> 3);
    const int tm = wg >> 4;        // 32 M-tiles
    const int tn = wg & 15;        // 16 N-tiles

    const size_t arow0 = (size_t)tm * 256;
    const size_t brow0 = (size_t)tn * 256;

    // staging: thread tid handles round-row rq = tid>>3, 16B chunk tid&7.
    // source col chunk pre-swizzled: (l&7) ^ (dest_row & 7), dest_row&7 == l>>3.
    const int rq = tid >> 3;                               // 0..63
    const int wq = (tid >> 6) << 3;                        // wave-uniform row base
    const int srcoff = (((tid & 7) ^ ((tid >> 3) & 7)) << 3);  // element offset

    auto stageA = [&](int sb, int c, int kt) {
        #pragma unroll
        for (int q = 0; q < 2; ++q) {
            const int dr = c * 64 + q * 128 + rq;
            gload16(A + ((arow0 + dr) << 12) + kt + srcoff,
                    (void*)&L[sb + ((c * 64 + q * 128 + wq) << 6)]);
        }
    };
    auto stageB = [&](int sb, int c, int kt) {
        #pragma unroll
        for (int q = 0; q < 2; ++q) {
            const int lr  = q * 64 + rq;
            const int dr  = c * 32 + (lr & 31) + (lr >> 5) * 64;
            const int wlr = q * 64 + wq;
            const int wdr = c * 32 + (wlr & 31) + (wlr >> 5) * 64;
            gload16(Bt + ((brow0 + dr) << 12) + kt + srcoff,
                    (void*)&L[sb + 16384 + (wdr << 6)]);
        }
    };

    // ds_read fragment base byte-offsets (swizzle folded in; XOR with k-chunk)
    int abase[8], bbase[4];
    #pragma unroll
    for (int m = 0; m < 8; ++m) {
        const int r = wr * 128 + m * 16 + fr;
        abase[m] = r * 128 + ((r & 7) << 4);
    }
    #pragma unroll
    for (int n = 0; n < 4; ++n) {
        const int r = wc * 64 + n * 16 + fr;
        bbase[n] = r * 128 + ((r & 7) << 4);
    }

    f32x4 acc[8][4];
    #pragma unroll
    for (int m = 0; m < 8; ++m)
        #pragma unroll
        for (int n = 0; n < 4; ++n)
            acc[m][n] = (f32x4){0.f, 0.f, 0.f, 0.f};

    // prologue: tile 0 into buf0, then require A0,B0 landed (newest 2 fly)
    stageA(0, 0, 0); stageB(0, 0, 0); stageB(0, 1, 0); stageA(0, 1, 0);
    asm volatile("s_waitcnt vmcnt(4)" ::: "memory");
    __builtin_amdgcn_s_barrier();
    __builtin_amdgcn_sched_barrier(0);

    for (int t = 0; t < 63; ++t) {
        const char* abuf = (const char*)L + (t & 1) * 65536;
        const char* bbuf = abuf + 32768;
        const int sb  = ((t & 1) ^ 1) * 32768;  // u16 index of stage buffer
        const int kt1 = (t + 1) * 64;
        PHASE(0, 0, stageA(sb, 0, kt1));
        PHASE(0, 1, stageB(sb, 0, kt1));
        PHASE(1, 0, stageB(sb, 1, kt1));
        PHASE(1, 1, stageA(sb, 1, kt1));
    }
    // tail tile 63 (buf1), no staging
    asm volatile("s_waitcnt vmcnt(0)" ::: "memory");
    __builtin_amdgcn_s_barrier();
    __builtin_amdgcn_sched_barrier(0);
    {
        const char* abuf = (const char*)L + 65536;
        const char* bbuf = abuf + 32768;
        PHASE(0, 0, (void)0);
        PHASE(0, 1, (void)0);
        PHASE(1, 0, (void)0);
        PHASE(1, 1, (void)0);
    }

    // epilogue: C/D layout col = lane&15, row = (lane>>4)*4 + reg
    const int orow0 = tm * 256 + wr * 128;
    const int ocol0 = tn * 256 + wc * 64;
    #pragma unroll
    for (int m = 0; m < 8; ++m) {
        #pragma unroll
        for (int n = 0; n < 4; ++n) {
            #pragma unroll
            for (int j = 0; j < 4; ++j) {
                const int row = orow0 + m * 16 + fg * 4 + j;
                const int col = ocol0 + n * 16 + fr;
                float v = acc[m][n][j];
                if (MODE == 1) {
                    v = fmaxf(v, 0.0f) * 2.0f;
                    ((unsigned short*)Cout)[((size_t)row << 12) + col] = f2bf(v);
                } else {
                    ((float*)Cout)[((size_t)row << 12) + col] = v;
                }
            }
        }
    }
}

// ---------------------------------------------------------------------------
extern "C" void kernel_launch(void* const* d_in, const int* in_sizes, int n_in,
                              void* d_out, int out_size, void* d_ws, size_t ws_size,
                              hipStream_t stream) {
    const float* x  = (const float*)d_in[0];
    const void*  k0 = d_in[1];
    const float* s0 = (const float*)d_in[2];
    const void*  k1 = d_in[3];
    const float* s1 = (const float*)d_in[4];
    const void*  k2 = d_in[5];
    const float* s2 = (const float*)d_in[6];

    const int M = in_sizes[0] / DD;   // 8192

    const size_t act_bytes = (size_t)M * DD * 2;
    const size_t w_bytes   = (size_t)DD * DD * 2;
    const size_t need      = act_bytes * 2 + w_bytes + 256;
    if (ws_size < need) return;

    char* ws = (char*)d_ws;
    unsigned short* xb = (unsigned short*)ws;                        // M x DD bf16 (later h2)
    unsigned short* h1 = (unsigned short*)(ws + act_bytes);          // M x DD bf16
    unsigned short* wt = (unsigned short*)(ws + act_bytes * 2);      // DD x DD bf16 (N x K)
    int* flag          = (int*)(ws + act_bytes * 2 + w_bytes);

    detect_kernel<<<1, 64, 0, stream>>>((const unsigned int*)k0, flag);
    pack_x_kernel<<<2048, 256, 0, stream>>>(x, xb, M * DD / 8);

    dim3 pw_grid(DD / 64, DD / 64);
    const int gemm_grid = (M / 256) * (DD / 256);   // 512

    // layer 0: h1 = relu(s0 * x @ W0) * 2
    pack_w_kernel<<<pw_grid, 256, 0, stream>>>(k0, wt, s0, 1.0f, DD, flag);
    gemm256_kernel<1><<<gemm_grid, 512, 0, stream>>>(xb, wt, h1);

    // layer 1: h2 = relu(ei_dense(h1, k1, s1)) * 2
    pack_w_kernel<<<pw_grid, 256, 0, stream>>>(k1, wt, s1, -4.0f, NE_IDX, flag);
    gemm256_kernel<1><<<gemm_grid, 512, 0, stream>>>(h1, wt, xb);

    // layer 2: out = ei_dense(h2, k2, s2), fp32
    pack_w_kernel<<<pw_grid, 256, 0, stream>>>(k2, wt, s2, -4.0f, NE_IDX, flag);
    gemm256_kernel<0><<<gemm_grid, 512, 0, stream>>>(xb, wt, (float*)d_out);
}

// Round 3
// 711.062 us; speedup vs baseline: 1.3428x; 1.2032x over previous
//
#include <hip/hip_runtime.h>
#include <stdint.h>

// D = 4096, TOKENS = (4,2048) -> M = 8192.
#define DD 4096
#define NE_IDX 3277   // round(4096*0.8)

typedef __attribute__((ext_vector_type(8))) short short8;
typedef __attribute__((ext_vector_type(4))) float f32x4;
typedef __attribute__((ext_vector_type(4))) unsigned int u32x4;

__device__ __forceinline__ unsigned short f2bf(float f) {
    unsigned int u = __float_as_uint(f);
    u += 0x7fffu + ((u >> 16) & 1u);
    return (unsigned short)(u >> 16);
}

__device__ __forceinline__ void gload16(const void* g, void* l) {
    __builtin_amdgcn_global_load_lds(
        (const __attribute__((address_space(1))) unsigned int*)g,
        (__attribute__((address_space(3))) unsigned int*)l,
        16, 0, 0);
}

// ---------------------------------------------------------------------------
__global__ void detect_kernel(const unsigned int* __restrict__ k0, int* __restrict__ flag) {
    if (blockIdx.x == 0 && threadIdx.x == 0) {
        int ok4 = 1;
        for (int i = 0; i < 256; ++i) {
            unsigned int v = k0[i];
            if (!(v == 0u || v == 1u || v == 0x3f800000u)) { ok4 = 0; break; }
        }
        *flag = ok4;
    }
}

// ---------------------------------------------------------------------------
__global__ void pack_x_kernel(const float* __restrict__ x, unsigned short* __restrict__ xb, int n8) {
    const int stride = gridDim.x * blockDim.x;
    for (int i = blockIdx.x * blockDim.x + threadIdx.x; i < n8; i += stride) {
        const float4* p = (const float4*)(x + (size_t)i * 8);
        float4 a = p[0], b = p[1];
        short8 r;
        r[0] = (short)f2bf(a.x); r[1] = (short)f2bf(a.y);
        r[2] = (short)f2bf(a.z); r[3] = (short)f2bf(a.w);
        r[4] = (short)f2bf(b.x); r[5] = (short)f2bf(b.y);
        r[6] = (short)f2bf(b.z); r[7] = (short)f2bf(b.w);
        *(short8*)(xb + (size_t)i * 8) = r;
    }
}

// ---------------------------------------------------------------------------
// wt[j*DD + i] = s * (i < ne ? 1 : inh) * (k[i][j] ? 1 : -1), 64x64 LDS transpose
// ---------------------------------------------------------------------------
__global__ void pack_w_kernel(const void* __restrict__ kin, unsigned short* __restrict__ wt,
                              const float* __restrict__ sptr, float inh, int ne,
                              const int* __restrict__ flag) {
    __shared__ unsigned short tile[64][68];
    const int elem4 = *flag;
    const float s = *sptr;
    const int i0 = blockIdx.x * 64;
    const int j0 = blockIdx.y * 64;
    const int t = threadIdx.x;
    {
        const int il = t >> 2;
        const int jc = (t & 3) * 16;
        const int gi = i0 + il;
        const float mag = s * ((gi < ne) ? 1.0f : inh);
        const unsigned short pos = f2bf(mag);
        const unsigned short neg = f2bf(-mag);
        if (elem4) {
            const unsigned int* k32 = (const unsigned int*)kin + (size_t)gi * DD + j0 + jc;
            #pragma unroll
            for (int q = 0; q < 4; ++q) {
                u32x4 v = *(const u32x4*)(k32 + q * 4);
                #pragma unroll
                for (int e = 0; e < 4; ++e)
                    tile[il][jc + q * 4 + e] = v[e] ? pos : neg;
            }
        } else {
            const unsigned char* k8 = (const unsigned char*)kin + (size_t)gi * DD + j0 + jc;
            u32x4 v = *(const u32x4*)k8;
            #pragma unroll
            for (int q = 0; q < 4; ++q) {
                unsigned int w = v[q];
                tile[il][jc + q * 4 + 0] = (w & 0xffu) ? pos : neg;
                tile[il][jc + q * 4 + 1] = ((w >> 8) & 0xffu) ? pos : neg;
                tile[il][jc + q * 4 + 2] = ((w >> 16) & 0xffu) ? pos : neg;
                tile[il][jc + q * 4 + 3] = ((w >> 24) & 0xffu) ? pos : neg;
            }
        }
    }
    __syncthreads();
    {
        const int jl = t >> 2;
        const int ic = (t & 3) * 16;
        short8 o0, o1;
        #pragma unroll
        for (int e = 0; e < 8; ++e) o0[e] = (short)tile[ic + e][jl];
        #pragma unroll
        for (int e = 0; e < 8; ++e) o1[e] = (short)tile[ic + 8 + e][jl];
        unsigned short* dst = wt + (size_t)(j0 + jl) * DD + i0 + ic;
        *(short8*)(dst) = o0;
        *(short8*)(dst + 8) = o1;
    }
}

// ---------------------------------------------------------------------------
// 256x256 tile, BK=64, 8 waves (2Mx4N), 4 phases/K-tile.
// Phase order (0,0),(0,1),(1,1),(1,0): A-half reused across phase pairs,
// B-half shared by the middle pair -> 28 ds_read_b128/tile (12/4/8/4).
// Per phase: [optional frag reads] -> stage 1 chunk -> vmcnt(4) -> barrier ->
// lgkmcnt(0) -> 16 MFMA (setprio) -> sched fence. End-barrier only at p3.
// Stage order A0',B0',B1',A1' at p0..p3 for tile t+1. Deadline proof:
//   p_i's vmcnt(4) (before its barrier) leaves newest 4 = last 2 stage chunks;
//   - at t.p3: newest={A1',B1'} => A0',B0' landed  -> t+1.p0 reads A0,B0 ok
//   - at t+1.p0: newest={A0'',A1'} => B1' landed   -> t+1.p1 reads B1 ok
//   - at t+1.p1: newest={B0'',A0''} => A1' landed  -> t+1.p2 reads A1 ok
//   p3's END barrier orders tile-t reads (complete via lgkm before arrival)
//   before tile-t+1 stage-writes into the same buffer.
// ---------------------------------------------------------------------------
#define PHASE(MH, NH, LA, LB, STAGE_STMT, EB) do {                              \
    if (LA) {                                                                   \
        _Pragma("unroll")                                                       \
        for (int m = 0; m < 4; ++m) {                                           \
            af[0][m] = *(const short8*)(Lc + (ab[(MH)*4+m] ^ kx0));             \
            af[1][m] = *(const short8*)(Lc + (ab[(MH)*4+m] ^ kx1));             \
        }                                                                       \
    }                                                                           \
    if (LB) {                                                                   \
        _Pragma("unroll")                                                       \
        for (int n = 0; n < 2; ++n) {                                           \
            bf[0][n] = *(const short8*)(Lc + (bb[(NH)*2+n] ^ kx0));             \
            bf[1][n] = *(const short8*)(Lc + (bb[(NH)*2+n] ^ kx1));             \
        }                                                                       \
    }                                                                           \
    STAGE_STMT;                                                                 \
    asm volatile("s_waitcnt vmcnt(4)" ::: "memory");                            \
    __builtin_amdgcn_s_barrier();                                               \
    asm volatile("s_waitcnt lgkmcnt(0)" ::: "memory");                          \
    __builtin_amdgcn_sched_barrier(0);                                          \
    __builtin_amdgcn_s_setprio(1);                                              \
    _Pragma("unroll")                                                           \
    for (int kk = 0; kk < 2; ++kk)                                              \
        _Pragma("unroll")                                                       \
        for (int m = 0; m < 4; ++m)                                             \
            _Pragma("unroll")                                                   \
            for (int n = 0; n < 2; ++n)                                         \
                acc[(MH)*4+m][(NH)*2+n] = __builtin_amdgcn_mfma_f32_16x16x32_bf16( \
                    af[kk][m], bf[kk][n], acc[(MH)*4+m][(NH)*2+n], 0, 0, 0);    \
    __builtin_amdgcn_s_setprio(0);                                              \
    __builtin_amdgcn_sched_barrier(0);                                          \
    if (EB) __builtin_amdgcn_s_barrier();                                       \
} while (0)

template <int MODE>
__global__ __launch_bounds__(512, 2)
void gemm256_kernel(const unsigned short* __restrict__ A,   // M x 4096 bf16
                    const unsigned short* __restrict__ Bt,  // 4096 x 4096 bf16 (N x K)
                    void* __restrict__ Cout)
{
    __shared__ unsigned short L[65536];  // 128 KiB: buf0{A,B} buf1{A,B}
    const char* Lc = (const char*)L;

    const int tid  = threadIdx.x;
    const int lane = tid & 63;
    const int fr   = lane & 15;
    const int fg   = lane >> 4;
    const int wave = tid >> 6;
    const int wr   = wave >> 2;    // 0..1
    const int wc   = wave & 3;     // 0..3

    // XCD swizzle (grid = 512, divisible by 8)
    int wg = blockIdx.x;
    const int per = gridDim.x >> 3;
    wg = (wg & 7) * per + (wg >> 3);
    const int tm = wg >> 4;        // 32 M-tiles
    const int tn = wg & 15;        // 16 N-tiles

    const size_t arow0 = (size_t)tm * 256;
    const size_t brow0 = (size_t)tn * 256;

    // staging: thread tid handles round-row rq = tid>>3, 16B chunk tid&7.
    const int rq = tid >> 3;
    const int wq = (tid >> 6) << 3;
    const int srcoff = (((tid & 7) ^ ((tid >> 3) & 7)) << 3);

    auto stageA = [&](int sb, int c, int kt) {
        #pragma unroll
        for (int q = 0; q < 2; ++q) {
            const int dr = c * 64 + q * 128 + rq;
            gload16(A + ((arow0 + dr) << 12) + kt + srcoff,
                    (void*)&L[sb + ((c * 64 + q * 128 + wq) << 6)]);
        }
    };
    auto stageB = [&](int sb, int c, int kt) {
        #pragma unroll
        for (int q = 0; q < 2; ++q) {
            const int lr  = q * 64 + rq;
            const int dr  = c * 32 + (lr & 31) + (lr >> 5) * 64;
            const int wlr = q * 64 + wq;
            const int wdr = c * 32 + (wlr & 31) + (wlr >> 5) * 64;
            gload16(Bt + ((brow0 + dr) << 12) + kt + srcoff,
                    (void*)&L[sb + 16384 + (wdr << 6)]);
        }
    };

    // precomputed ds_read byte addresses (swizzle + buffer bit folded in)
    const int kx0 = fg << 4;
    const int kx1 = (4 + fg) << 4;
    int ab[8], bb[4];
    #pragma unroll
    for (int m = 0; m < 8; ++m) {
        const int r = wr * 128 + m * 16 + fr;
        ab[m] = r * 128 + ((r & 7) << 4);
    }
    #pragma unroll
    for (int n = 0; n < 4; ++n) {
        const int r = wc * 64 + n * 16 + fr;
        bb[n] = 32768 + r * 128 + ((r & 7) << 4);
    }

    short8 af[2][4], bf[2][2];
    f32x4 acc[8][4];
    #pragma unroll
    for (int m = 0; m < 8; ++m)
        #pragma unroll
        for (int n = 0; n < 4; ++n)
            acc[m][n] = (f32x4){0.f, 0.f, 0.f, 0.f};

    // prologue: tile 0 into buf0; vmcnt(4) leaves newest {B1,A1} in flight
    stageA(0, 0, 0); stageB(0, 0, 0); stageB(0, 1, 0); stageA(0, 1, 0);
    asm volatile("s_waitcnt vmcnt(4)" ::: "memory");
    __builtin_amdgcn_s_barrier();
    __builtin_amdgcn_sched_barrier(0);

    for (int t = 0; t < 63; ++t) {
        const int sb  = ((t & 1) ^ 1) * 32768;  // u16 index of stage buffer
        const int kt1 = (t + 1) * 64;
        PHASE(0, 0, 1, 1, stageA(sb, 0, kt1), 0);
        PHASE(0, 1, 0, 1, stageB(sb, 0, kt1), 0);
        PHASE(1, 1, 1, 0, stageB(sb, 1, kt1), 0);
        PHASE(1, 0, 0, 1, stageA(sb, 1, kt1), 1);
        #pragma unroll
        for (int i = 0; i < 8; ++i) ab[i] ^= 65536;
        #pragma unroll
        for (int i = 0; i < 4; ++i) bb[i] ^= 65536;
    }
    // tail tile 63 (bases already point at buf1), no staging
    asm volatile("s_waitcnt vmcnt(0)" ::: "memory");
    __builtin_amdgcn_s_barrier();
    __builtin_amdgcn_sched_barrier(0);
    PHASE(0, 0, 1, 1, (void)0, 0);
    PHASE(0, 1, 0, 1, (void)0, 0);
    PHASE(1, 1, 1, 0, (void)0, 0);
    PHASE(1, 0, 0, 1, (void)0, 0);

    // epilogue: C/D layout col = lane&15, row = (lane>>4)*4 + reg
    const int orow0 = tm * 256 + wr * 128;
    const int ocol0 = tn * 256 + wc * 64;
    #pragma unroll
    for (int m = 0; m < 8; ++m) {
        #pragma unroll
        for (int n = 0; n < 4; ++n) {
            #pragma unroll
            for (int j = 0; j < 4; ++j) {
                const int row = orow0 + m * 16 + fg * 4 + j;
                const int col = ocol0 + n * 16 + fr;
                float v = acc[m][n][j];
                if (MODE == 1) {
                    v = fmaxf(v, 0.0f) * 2.0f;
                    ((unsigned short*)Cout)[((size_t)row << 12) + col] = f2bf(v);
                } else {
                    ((float*)Cout)[((size_t)row << 12) + col] = v;
                }
            }
        }
    }
}

// ---------------------------------------------------------------------------
extern "C" void kernel_launch(void* const* d_in, const int* in_sizes, int n_in,
                              void* d_out, int out_size, void* d_ws, size_t ws_size,
                              hipStream_t stream) {
    const float* x  = (const float*)d_in[0];
    const void*  k0 = d_in[1];
    const float* s0 = (const float*)d_in[2];
    const void*  k1 = d_in[3];
    const float* s1 = (const float*)d_in[4];
    const void*  k2 = d_in[5];
    const float* s2 = (const float*)d_in[6];

    const int M = in_sizes[0] / DD;   // 8192

    const size_t act_bytes = (size_t)M * DD * 2;
    const size_t w_bytes   = (size_t)DD * DD * 2;
    const size_t need      = act_bytes * 2 + w_bytes + 256;
    if (ws_size < need) return;

    char* ws = (char*)d_ws;
    unsigned short* xb = (unsigned short*)ws;                        // M x DD bf16 (later h2)
    unsigned short* h1 = (unsigned short*)(ws + act_bytes);          // M x DD bf16
    unsigned short* wt = (unsigned short*)(ws + act_bytes * 2);      // DD x DD bf16 (N x K)
    int* flag          = (int*)(ws + act_bytes * 2 + w_bytes);

    detect_kernel<<<1, 64, 0, stream>>>((const unsigned int*)k0, flag);
    pack_x_kernel<<<2048, 256, 0, stream>>>(x, xb, M * DD / 8);

    dim3 pw_grid(DD / 64, DD / 64);
    const int gemm_grid = (M / 256) * (DD / 256);   // 512

    // layer 0: h1 = relu(s0 * x @ W0) * 2
    pack_w_kernel<<<pw_grid, 256, 0, stream>>>(k0, wt, s0, 1.0f, DD, flag);
    gemm256_kernel<1><<<gemm_grid, 512, 0, stream>>>(xb, wt, h1);

    // layer 1: h2 = relu(ei_dense(h1, k1, s1)) * 2
    pack_w_kernel<<<pw_grid, 256, 0, stream>>>(k1, wt, s1, -4.0f, NE_IDX, flag);
    gemm256_kernel<1><<<gemm_grid, 512, 0, stream>>>(h1, wt, xb);

    // layer 2: out = ei_dense(h2, k2, s2), fp32
    pack_w_kernel<<<pw_grid, 256, 0, stream>>>(k2, wt, s2, -4.0f, NE_IDX, flag);
    gemm256_kernel<0><<<gemm_grid, 512, 0, stream>>>(xb, wt, (float*)d_out);
}